// Round 2
// baseline (191.967 us; speedup 1.0000x reference)
//
#include <hip/hip_runtime.h>
#include <hip/hip_bf16.h>

#define B 64
#define F 2048
#define BN 64
#define BK 32
#define KSPLIT 8
#define KCHUNK (F / KSPLIT)   // 256
#define NITER (KCHUNK / BK)   // 8
#define LDSW 40               // LDS row stride in shorts (80 B, 16B-aligned rows)
#define GS 4                  // g-slices per attn block
#define NSEG 4                // 512-g compaction regions per b
#define RPROD 192             // producers per region: 8 fblk * 8 kb * 3 mats

typedef __attribute__((ext_vector_type(8))) short bf16x8;
typedef __attribute__((ext_vector_type(4))) float f32x4;

#define PART_FLOATS (KSPLIT * 3 * B * F)  // 12.6 MB
#define KVC_FLOATS (B * 2 * F)            // 1 MB
#define QS_FLOATS (B * F)                 // 0.5 MB

#if __has_builtin(__builtin_amdgcn_exp2f)
#define EXP2(x) __builtin_amdgcn_exp2f(x)   // raw v_exp_f32, no denorm expansion
#else
#define EXP2(x) exp2f(x)
#endif

// RTZ hi/lo split of two floats, packed via v_perm. 3 ops/float.
__device__ __forceinline__ void split2(float f0, float f1, int& hi, int& lo) {
  union { float f; unsigned u; } a, b;
  a.f = f0; b.f = f1;
  union { unsigned u; float f; } ha, hb;
  ha.u = a.u & 0xFFFF0000u;
  hb.u = b.u & 0xFFFF0000u;
  union { float f; unsigned u; } la, lb;
  la.f = f0 - ha.f;
  lb.f = f1 - hb.f;
  hi = (int)__builtin_amdgcn_perm(b.u, a.u, 0x07060302u);
  lo = (int)__builtin_amdgcn_perm(lb.u, la.u, 0x07060302u);
}

// Fused QKV GEMM + prep.
// GEMM: C[b,f] = sum_k x[b,k]*W[f,k], bf16 hi/lo split (3 MFMAs ~ fp32 accuracy),
// split-K partials -> part[(kb*3+mat)*B*F]. Unchanged from the verified version.
// Prep (fused via last-arrivals): each block tickets ready[region] after a
// device-scope release; the last 64 arrivals per region each take one b and
// reduce the 24 partial streams for 512 g's, write qs[b,*], compact unmasked
// (k,v) pairs into kvc, and record per-region cnt/kmax/kmin/vsum.
// Deadlock-free at any occupancy: non-runner blocks retire and free slots.
__global__ __launch_bounds__(256) void qkv_gemm_prep_kernel(
    const float* __restrict__ x, const float* __restrict__ Wq,
    const float* __restrict__ Wk, const float* __restrict__ Wv,
    const int* __restrict__ mask,
    float* __restrict__ part, float* __restrict__ kvc,
    float* __restrict__ qs, float* __restrict__ vsum4,
    float* __restrict__ kmax4, float* __restrict__ kmin4,
    int* __restrict__ cnt4, int* __restrict__ ready) {
  __shared__ __align__(16) short xs_hi[2][B][LDSW];
  __shared__ __align__(16) short xs_lo[2][B][LDSW];
  __shared__ __align__(16) short ws_hi[2][BN][LDSW];
  __shared__ __align__(16) short ws_lo[2][BN][LDSW];
  __shared__ int ticket;
  __shared__ int pcnt;
  __shared__ float svs[4], smx[4], smn[4];

  const int tid  = threadIdx.x;
  const int f0   = blockIdx.x * BN;
  const int kb   = blockIdx.y;
  const int mat  = blockIdx.z;
  const float* W = (mat == 0) ? Wq : (mat == 1) ? Wk : Wv;

  const int lrow = tid >> 2;           // staging row 0..63
  const int lc0  = (tid & 3) << 3;     // staging col (shorts) 0,8,16,24

  const int wave = tid >> 6;
  const int lane = tid & 63;
  const int l15  = lane & 15;
  const int quad = lane >> 4;

  const float* xg = x + lrow * F + kb * KCHUNK + lc0;
  const float* wg = W + (f0 + lrow) * F + kb * KCHUNK + lc0;

  f32x4 acc[4];
#pragma unroll
  for (int i = 0; i < 4; ++i) acc[i] = (f32x4){0.f, 0.f, 0.f, 0.f};

  float4 px[2][2], pw[2][2];
  px[0][0] = *(const float4*)(xg);
  px[0][1] = *(const float4*)(xg + 4);
  pw[0][0] = *(const float4*)(wg);
  pw[0][1] = *(const float4*)(wg + 4);

#pragma unroll
  for (int it = 0; it < NITER; ++it) {
    const int cur = it & 1, nxt = cur ^ 1;
    if (it + 1 < NITER) {  // prefetch next chunk into alternate regs
      const float* xp = xg + (it + 1) * BK;
      const float* wp = wg + (it + 1) * BK;
      px[nxt][0] = *(const float4*)(xp);
      px[nxt][1] = *(const float4*)(xp + 4);
      pw[nxt][0] = *(const float4*)(wp);
      pw[nxt][1] = *(const float4*)(wp + 4);
    }
    int4 xh, xl, wh, wl;
    split2(px[cur][0].x, px[cur][0].y, xh.x, xl.x);
    split2(px[cur][0].z, px[cur][0].w, xh.y, xl.y);
    split2(px[cur][1].x, px[cur][1].y, xh.z, xl.z);
    split2(px[cur][1].z, px[cur][1].w, xh.w, xl.w);
    split2(pw[cur][0].x, pw[cur][0].y, wh.x, wl.x);
    split2(pw[cur][0].z, pw[cur][0].w, wh.y, wl.y);
    split2(pw[cur][1].x, pw[cur][1].y, wh.z, wl.z);
    split2(pw[cur][1].z, pw[cur][1].w, wh.w, wl.w);
    *(int4*)&xs_hi[cur][lrow][lc0] = xh;
    *(int4*)&xs_lo[cur][lrow][lc0] = xl;
    *(int4*)&ws_hi[cur][lrow][lc0] = wh;
    *(int4*)&ws_lo[cur][lrow][lc0] = wl;
    __syncthreads();  // writes[cur] visible; prior iter's reads drained

    bf16x8 a_hi = *(const bf16x8*)&xs_hi[cur][(wave << 4) + l15][quad << 3];
    bf16x8 a_lo = *(const bf16x8*)&xs_lo[cur][(wave << 4) + l15][quad << 3];
#pragma unroll
    for (int nt = 0; nt < 4; ++nt) {
      bf16x8 b_hi = *(const bf16x8*)&ws_hi[cur][(nt << 4) + l15][quad << 3];
      bf16x8 b_lo = *(const bf16x8*)&ws_lo[cur][(nt << 4) + l15][quad << 3];
      acc[nt] = __builtin_amdgcn_mfma_f32_16x16x32_bf16(a_hi, b_hi, acc[nt], 0, 0, 0);
      acc[nt] = __builtin_amdgcn_mfma_f32_16x16x32_bf16(a_hi, b_lo, acc[nt], 0, 0, 0);
      acc[nt] = __builtin_amdgcn_mfma_f32_16x16x32_bf16(a_lo, b_hi, acc[nt], 0, 0, 0);
    }
  }

  // epilogue: C/D layout col=lane&15, row=quad*4+reg
  float* outp = part + (size_t)(kb * 3 + mat) * B * F;
#pragma unroll
  for (int nt = 0; nt < 4; ++nt) {
    int f = f0 + (nt << 4) + l15;
#pragma unroll
    for (int r = 0; r < 4; ++r) {
      int brow = (wave << 4) + (quad << 2) + r;
      outp[brow * F + f] = acc[nt][r];
    }
  }

  // ---------- fused prep handoff ----------
  const int seg = blockIdx.x >> 3;   // 512-g region 0..3
  __syncthreads();                   // all epilogue stores issued+drained (vmcnt0)
  if (tid == 0) {
    __threadfence();                 // device-scope release of this block's partials
    ticket = atomicAdd(&ready[seg], 1);
  }
  __syncthreads();
  const int old = ticket;
  if (old < RPROD - B) return;       // not a runner
  const int b = old - (RPROD - B);   // runner owns batch row b for this region

  if (tid == 0) {
    while (__hip_atomic_load(ready + seg, __ATOMIC_ACQUIRE,
                             __HIP_MEMORY_SCOPE_AGENT) < RPROD) {
      __builtin_amdgcn_s_sleep(2);
    }
    pcnt = 0;
  }
  __syncthreads();
  __threadfence();                   // acquire: drop stale cached partials

  // prep for (b, seg): 2 g's per thread, 512 g's total
  const int g0 = (seg << 9) + (tid << 1);
  float2 kq = {0.f, 0.f}, vq = {0.f, 0.f}, qq = {0.f, 0.f};
#pragma unroll
  for (int p = 0; p < KSPLIT; ++p) {
    const float* pb = part + (size_t)p * 3 * B * F + (size_t)b * F + g0;
    const float2 q2 = *(const float2*)(pb);
    const float2 k2 = *(const float2*)(pb + (size_t)B * F);
    const float2 v2 = *(const float2*)(pb + (size_t)2 * B * F);
    qq.x += q2.x; qq.y += q2.y;
    kq.x += k2.x; kq.y += k2.y;
    vq.x += v2.x; vq.y += v2.y;
  }
  *(float2*)&qs[b * F + g0] = qq;
  float vs = vq.x + vq.y;

  const int2 m2 = *(const int2*)&mask[b * F + g0];
  const bool a0 = (m2.x != 0), a1 = (m2.y != 0);
  const unsigned long long bal0 = __ballot(a0);
  const unsigned long long bal1 = __ballot(a1);
  const int tot = __popcll(bal0) + __popcll(bal1);
  int basep = 0;
  if (lane == 0) basep = atomicAdd(&pcnt, tot);
  basep = __shfl(basep, 0);

  float* kvb = kvc + (size_t)b * 2 * F + (seg << 10);
  const unsigned long long ltm = (1ull << lane) - 1ull;
  float kmx = -3.4e38f, kmn = 3.4e38f;
  if (a0) {
    int pos = basep + __popcll(bal0 & ltm);
    *(float2*)&kvb[2 * pos] = (float2){kq.x, vq.x};
    kmx = fmaxf(kmx, kq.x); kmn = fminf(kmn, kq.x);
  }
  if (a1) {
    int pos = basep + __popcll(bal0) + __popcll(bal1 & ltm);
    *(float2*)&kvb[2 * pos] = (float2){kq.y, vq.y};
    kmx = fmaxf(kmx, kq.y); kmn = fminf(kmn, kq.y);
  }

#pragma unroll
  for (int o = 32; o > 0; o >>= 1) {
    vs += __shfl_xor(vs, o);
    kmx = fmaxf(kmx, __shfl_xor(kmx, o));
    kmn = fminf(kmn, __shfl_xor(kmn, o));
  }
  if (lane == 0) { svs[wave] = vs; smx[wave] = kmx; smn[wave] = kmn; }
  __syncthreads();
  if (tid == 0) {
    vsum4[(b << 2) + seg] = svs[0] + svs[1] + svs[2] + svs[3];
    kmax4[(b << 2) + seg] = fmaxf(fmaxf(smx[0], smx[1]), fmaxf(smx[2], smx[3]));
    kmin4[(b << 2) + seg] = fminf(fminf(smn[0], smn[1]), fminf(smn[2], smn[3]));
    cnt4[(b << 2) + seg]  = pcnt;
  }
}

// attended[b,f]: the (k,v) stream is wave-uniform -> read through uniform
// float4 pointers (scalar s_load path, LDS pipe idle). q comes pre-reduced
// from qs (1 load instead of 8 partial fetches). 3 VALU + 1 v_exp per element.
__global__ __launch_bounds__(1024, 8) void attn_kernel(
    const float* __restrict__ qs, const float* __restrict__ kvc,
    const float* __restrict__ vsum4, const float* __restrict__ kmax4,
    const float* __restrict__ kmin4, const int* __restrict__ cnt4,
    float* __restrict__ out) {
  __shared__ float rn[GS][256];
  __shared__ float rd[GS][256];

  const int b     = blockIdx.x;
  const int tid   = threadIdx.x;
  const int fl    = tid & 255;
  const int slice = __builtin_amdgcn_readfirstlane(tid >> 8);  // wave-uniform SGPR
  const int fi    = blockIdx.y * 256 + fl;

  const float s = qs[b * F + fi];

  int cnts[NSEG];
  float km = -3.4e38f, kn = 3.4e38f;
  int ntot = 0;
  float vstot = 0.f;
#pragma unroll
  for (int g4 = 0; g4 < NSEG; ++g4) {
    cnts[g4] = cnt4[(b << 2) + g4];
    ntot += cnts[g4];
    km = fmaxf(km, kmax4[(b << 2) + g4]);
    kn = fminf(kn, kmin4[(b << 2) + g4]);
    vstot += vsum4[(b << 2) + g4];
  }

  const float L2E = 1.44269504088896f;
  const float se  = s * L2E;
  const float nm2 = -se * ((s >= 0.f) ? km : kn);

  float n0 = 0.f, n1 = 0.f, n2 = 0.f, n3 = 0.f;
  float d0 = 0.f, d1 = 0.f, d2 = 0.f, d3 = 0.f;
  const float* kvbase = kvc + (size_t)b * 2 * F;
#pragma unroll
  for (int seg = 0; seg < NSEG; ++seg) {
    const int cnt   = cnts[seg];
    const int quads = cnt >> 1;                 // float4 groups (2 pairs)
    const int q0 = (slice * quads) / GS;
    const int q1 = ((slice + 1) * quads) / GS;
    const float4* bp = (const float4*)(kvbase + (seg << 10));
    int q = q0;
    for (; q + 4 <= q1; q += 4) {               // 16 floats via uniform loads
      float4 p0 = bp[q];
      float4 p1 = bp[q + 1];
      float4 p2 = bp[q + 2];
      float4 p3 = bp[q + 3];
      float e0 = EXP2(fmaf(se, p0.x, nm2));
      float e1 = EXP2(fmaf(se, p0.z, nm2));
      float e2 = EXP2(fmaf(se, p1.x, nm2));
      float e3 = EXP2(fmaf(se, p1.z, nm2));
      float e4 = EXP2(fmaf(se, p2.x, nm2));
      float e5 = EXP2(fmaf(se, p2.z, nm2));
      float e6 = EXP2(fmaf(se, p3.x, nm2));
      float e7 = EXP2(fmaf(se, p3.z, nm2));
      n0 = fmaf(e0, p0.y, n0); d0 += e0;
      n1 = fmaf(e1, p0.w, n1); d1 += e1;
      n2 = fmaf(e2, p1.y, n2); d2 += e2;
      n3 = fmaf(e3, p1.w, n3); d3 += e3;
      n0 = fmaf(e4, p2.y, n0); d0 += e4;
      n1 = fmaf(e5, p2.w, n1); d1 += e5;
      n2 = fmaf(e6, p3.y, n2); d2 += e6;
      n3 = fmaf(e7, p3.w, n3); d3 += e7;
    }
    for (; q < q1; ++q) {
      float4 p0 = bp[q];
      float e0 = EXP2(fmaf(se, p0.x, nm2));
      float e1 = EXP2(fmaf(se, p0.z, nm2));
      n0 = fmaf(e0, p0.y, n0); d0 += e0;
      n1 = fmaf(e1, p0.w, n1); d1 += e1;
    }
    if ((slice == GS - 1) && (cnt & 1)) {       // odd tail pair
      float2 p = *(const float2*)(kvbase + (seg << 10) + 2 * (cnt - 1));
      float e = EXP2(fmaf(se, p.x, nm2));
      n2 = fmaf(e, p.y, n2); d2 += e;
    }
  }
  rn[slice][fl] = (n0 + n1) + (n2 + n3);
  rd[slice][fl] = (d0 + d1) + (d2 + d3);
  __syncthreads();
  if (slice == 0) {
    float N = (rn[0][fl] + rn[1][fl]) + (rn[2][fl] + rn[3][fl]);
    float D = (rd[0][fl] + rd[1][fl]) + (rd[2][fl] + rd[3][fl]);
    out[b * F + fi] = (ntot > 0) ? (N / D) : (vstot * (1.0f / (float)F));
  }
}

extern "C" void kernel_launch(void* const* d_in, const int* in_sizes, int n_in,
                              void* d_out, int out_size, void* d_ws, size_t ws_size,
                              hipStream_t stream) {
  const float* x  = (const float*)d_in[0];
  const int* mask = (const int*)d_in[1];
  const float* Wq = (const float*)d_in[2];
  const float* Wk = (const float*)d_in[3];
  const float* Wv = (const float*)d_in[4];
  float* out = (float*)d_out;

  float* part  = (float*)d_ws;                 // 12.6 MB
  float* kvc   = part + PART_FLOATS;           // 1 MB
  float* qs    = kvc + KVC_FLOATS;             // 0.5 MB
  float* vsum4 = qs + QS_FLOATS;               // B*NSEG floats
  float* kmx4  = vsum4 + B * NSEG;
  float* kmn4  = kmx4 + B * NSEG;
  int*   cnt4  = (int*)(kmn4 + B * NSEG);
  int*   ready = cnt4 + B * NSEG;              // 4 region counters

  hipMemsetAsync(ready, 0, NSEG * sizeof(int), stream);

  dim3 gg(F / BN, KSPLIT, 3);
  qkv_gemm_prep_kernel<<<gg, 256, 0, stream>>>(x, Wq, Wk, Wv, mask, part, kvc,
                                               qs, vsum4, kmx4, kmn4, cnt4, ready);
  dim3 ga(B, F / 256);
  attn_kernel<<<ga, 1024, 0, stream>>>(qs, kvc, vsum4, kmx4, kmn4, cnt4, out);
}

// Round 3
// 122.647 us; speedup vs baseline: 1.5652x; 1.5652x over previous
//
#include <hip/hip_runtime.h>
#include <hip/hip_bf16.h>

#define B 64
#define F 2048
#define BN 32
#define BK 32
#define KSPLIT 4
#define KCHUNK (F / KSPLIT)   // 512
#define NITER (KCHUNK / BK)   // 16
#define LDSW 40               // LDS row stride in shorts (80 B, 16B-aligned rows)
#define GS 4                  // g-slices per attn block
#define NSEG 2                // compaction segments per b
#define SEGG 1024             // g's per segment

typedef __attribute__((ext_vector_type(8))) short bf16x8;
typedef __attribute__((ext_vector_type(4))) float f32x4;

#define PART_FLOATS (KSPLIT * 3 * B * F)  // 6.3 MB
#define KVC_FLOATS (B * 2 * F)            // 1 MB
#define QS_FLOATS (B * F)                 // 0.5 MB

#if __has_builtin(__builtin_amdgcn_exp2f)
#define EXP2(x) __builtin_amdgcn_exp2f(x)   // raw v_exp_f32, no denorm expansion
#else
#define EXP2(x) exp2f(x)
#endif

// RTZ hi/lo split of two floats, packed via v_perm. 3 ops/float.
__device__ __forceinline__ void split2(float f0, float f1, int& hi, int& lo) {
  union { float f; unsigned u; } a, b;
  a.f = f0; b.f = f1;
  union { unsigned u; float f; } ha, hb;
  ha.u = a.u & 0xFFFF0000u;
  hb.u = b.u & 0xFFFF0000u;
  union { float f; unsigned u; } la, lb;
  la.f = f0 - ha.f;
  lb.f = f1 - hb.f;
  hi = (int)__builtin_amdgcn_perm(b.u, a.u, 0x07060302u);
  lo = (int)__builtin_amdgcn_perm(lb.u, la.u, 0x07060302u);
}

// C[b,f] = sum_k x[b,k]*W[f,k], bf16 hi/lo split (3 MFMAs ~ fp32 accuracy).
// Split-K partials -> part[(kb*3+mat)*B*F]. LDS double-buffered, 1 barrier/iter.
// BN=32 x KSPLIT=4 -> 768 blocks = 3/CU (same concurrency as the verified
// BN=64 x KSPLIT=8 config) with HALF the split-K partial traffic.
// NO inter-block sync (round-2's fused handoff caused an L2-invalidate storm).
__global__ __launch_bounds__(256) void qkv_gemm_kernel(
    const float* __restrict__ x, const float* __restrict__ Wq,
    const float* __restrict__ Wk, const float* __restrict__ Wv,
    float* __restrict__ part) {
  __shared__ __align__(16) short xs_hi[2][B][LDSW];
  __shared__ __align__(16) short xs_lo[2][B][LDSW];
  __shared__ __align__(16) short ws_hi[2][BN][LDSW];
  __shared__ __align__(16) short ws_lo[2][BN][LDSW];

  const int tid  = threadIdx.x;
  const int f0   = blockIdx.x * BN;
  const int kb   = blockIdx.y;
  const int mat  = blockIdx.z;
  const float* W = (mat == 0) ? Wq : (mat == 1) ? Wk : Wv;

  const int lrow = tid >> 2;           // x staging row 0..63
  const int lc0  = (tid & 3) << 3;     // x staging col (shorts) 0,8,16,24
  const int wrow = tid >> 3;           // W staging row 0..31
  const int wc0  = (tid & 7) << 2;     // W staging col (shorts) 0,4,...,28

  const int wave = tid >> 6;
  const int lane = tid & 63;
  const int l15  = lane & 15;
  const int quad = lane >> 4;

  const float* xg = x + lrow * F + kb * KCHUNK + lc0;
  const float* wg = W + (f0 + wrow) * F + kb * KCHUNK + wc0;

  f32x4 acc[2];
#pragma unroll
  for (int i = 0; i < 2; ++i) acc[i] = (f32x4){0.f, 0.f, 0.f, 0.f};

  float4 px[2][2], pw[2];
  px[0][0] = *(const float4*)(xg);
  px[0][1] = *(const float4*)(xg + 4);
  pw[0]    = *(const float4*)(wg);

#pragma unroll
  for (int it = 0; it < NITER; ++it) {
    const int cur = it & 1, nxt = cur ^ 1;
    if (it + 1 < NITER) {  // prefetch next chunk into alternate regs
      const float* xp = xg + (it + 1) * BK;
      px[nxt][0] = *(const float4*)(xp);
      px[nxt][1] = *(const float4*)(xp + 4);
      pw[nxt]    = *(const float4*)(wg + (it + 1) * BK);
    }
    int4 xh, xl;
    int2 wh, wl;
    split2(px[cur][0].x, px[cur][0].y, xh.x, xl.x);
    split2(px[cur][0].z, px[cur][0].w, xh.y, xl.y);
    split2(px[cur][1].x, px[cur][1].y, xh.z, xl.z);
    split2(px[cur][1].z, px[cur][1].w, xh.w, xl.w);
    split2(pw[cur].x, pw[cur].y, wh.x, wl.x);
    split2(pw[cur].z, pw[cur].w, wh.y, wl.y);
    *(int4*)&xs_hi[cur][lrow][lc0] = xh;
    *(int4*)&xs_lo[cur][lrow][lc0] = xl;
    *(int2*)&ws_hi[cur][wrow][wc0] = wh;
    *(int2*)&ws_lo[cur][wrow][wc0] = wl;
    __syncthreads();  // writes[cur] visible; prior iter's reads drained

    bf16x8 a_hi = *(const bf16x8*)&xs_hi[cur][(wave << 4) + l15][quad << 3];
    bf16x8 a_lo = *(const bf16x8*)&xs_lo[cur][(wave << 4) + l15][quad << 3];
#pragma unroll
    for (int nt = 0; nt < 2; ++nt) {
      bf16x8 b_hi = *(const bf16x8*)&ws_hi[cur][(nt << 4) + l15][quad << 3];
      bf16x8 b_lo = *(const bf16x8*)&ws_lo[cur][(nt << 4) + l15][quad << 3];
      acc[nt] = __builtin_amdgcn_mfma_f32_16x16x32_bf16(a_hi, b_hi, acc[nt], 0, 0, 0);
      acc[nt] = __builtin_amdgcn_mfma_f32_16x16x32_bf16(a_hi, b_lo, acc[nt], 0, 0, 0);
      acc[nt] = __builtin_amdgcn_mfma_f32_16x16x32_bf16(a_lo, b_hi, acc[nt], 0, 0, 0);
    }
  }

  // epilogue: C/D layout col=lane&15, row=quad*4+reg
  float* outp = part + (size_t)(kb * 3 + mat) * B * F;
#pragma unroll
  for (int nt = 0; nt < 2; ++nt) {
    int f = f0 + (nt << 4) + l15;
#pragma unroll
    for (int r = 0; r < 4; ++r) {
      int brow = (wave << 4) + (quad << 2) + r;
      outp[brow * F + f] = acc[nt][r];
    }
  }
}

// Per (b, seg of 1024 g's): sum q/k/v split-K partials (float4, 4 g/lane),
// write reduced q to qs[b,*] (attn prologue: 1 load instead of KSPLIT),
// compact unmasked (k,v) pairs into kvc[b*2F + seg*2048 ..],
// record per-seg cnt/kmax/kmin/vsum.
__global__ __launch_bounds__(256) void prep_kernel(
    const float* __restrict__ part, const int* __restrict__ mask,
    float* __restrict__ kvc, float* __restrict__ qs,
    float* __restrict__ vsum2, float* __restrict__ kmax2,
    float* __restrict__ kmin2, int* __restrict__ cnt2) {
  __shared__ int cnt;
  __shared__ float svs[4], smx[4], smn[4];

  const int b    = blockIdx.x;
  const int seg  = blockIdx.y;
  const int tid  = threadIdx.x;
  const int wave = tid >> 6;
  const int lane = tid & 63;

  if (tid == 0) cnt = 0;
  __syncthreads();

  const int g0 = seg * SEGG + (tid << 2);   // 4 consecutive g's per lane
  float4 qq = {0.f, 0.f, 0.f, 0.f};
  float4 kq = {0.f, 0.f, 0.f, 0.f}, vq = {0.f, 0.f, 0.f, 0.f};
#pragma unroll
  for (int p = 0; p < KSPLIT; ++p) {
    const float4 qp = *(const float4*)&part[((p * 3 + 0) * B + b) * F + g0];
    const float4 kp = *(const float4*)&part[((p * 3 + 1) * B + b) * F + g0];
    const float4 vp = *(const float4*)&part[((p * 3 + 2) * B + b) * F + g0];
    qq.x += qp.x; qq.y += qp.y; qq.z += qp.z; qq.w += qp.w;
    kq.x += kp.x; kq.y += kp.y; kq.z += kp.z; kq.w += kp.w;
    vq.x += vp.x; vq.y += vp.y; vq.z += vp.z; vq.w += vp.w;
  }
  *(float4*)&qs[b * F + g0] = qq;
  float vs = (vq.x + vq.y) + (vq.z + vq.w);   // all v, masked or not (fallback path)

  const int4 m4 = *(const int4*)&mask[b * F + g0];
  const float kk[4] = {kq.x, kq.y, kq.z, kq.w};
  const float vv[4] = {vq.x, vq.y, vq.z, vq.w};
  const bool  act[4] = {m4.x != 0, m4.y != 0, m4.z != 0, m4.w != 0};

  unsigned long long bal[4];
  int tot = 0;
#pragma unroll
  for (int j = 0; j < 4; ++j) {
    bal[j] = __ballot(act[j]);
    tot += __popcll(bal[j]);
  }
  int base = 0;
  if (lane == 0) base = atomicAdd(&cnt, tot);
  base = __shfl(base, 0);

  float* kvb = kvc + (size_t)b * 2 * F + seg * 2 * SEGG;
  const unsigned long long ltm = (1ull << lane) - 1ull;
  float kmx = -3.4e38f, kmn = 3.4e38f;
  int off = base;
#pragma unroll
  for (int j = 0; j < 4; ++j) {
    if (act[j]) {
      int pos = off + __popcll(bal[j] & ltm);
      *(float2*)&kvb[2 * pos] = (float2){kk[j], vv[j]};
      kmx = fmaxf(kmx, kk[j]);
      kmn = fminf(kmn, kk[j]);
    }
    off += __popcll(bal[j]);
  }

#pragma unroll
  for (int o = 32; o > 0; o >>= 1) {
    vs += __shfl_xor(vs, o);
    kmx = fmaxf(kmx, __shfl_xor(kmx, o));
    kmn = fminf(kmn, __shfl_xor(kmn, o));
  }
  if (lane == 0) { svs[wave] = vs; smx[wave] = kmx; smn[wave] = kmn; }
  __syncthreads();
  if (tid == 0) {
    vsum2[b * NSEG + seg] = svs[0] + svs[1] + svs[2] + svs[3];
    kmax2[b * NSEG + seg] = fmaxf(fmaxf(smx[0], smx[1]), fmaxf(smx[2], smx[3]));
    kmin2[b * NSEG + seg] = fminf(fminf(smn[0], smn[1]), fminf(smn[2], smn[3]));
    cnt2[b * NSEG + seg]  = cnt;
  }
}

// attended[b,f]: the (k,v) stream is wave-uniform -> read through uniform
// float4 pointers (scalar s_load path, LDS pipe idle). q comes pre-reduced
// from qs. 3 VALU + 1 v_exp per element (structural floor for this form).
__global__ __launch_bounds__(1024, 8) void attn_kernel(
    const float* __restrict__ qs, const float* __restrict__ kvc,
    const float* __restrict__ vsum2, const float* __restrict__ kmax2,
    const float* __restrict__ kmin2, const int* __restrict__ cnt2,
    float* __restrict__ out) {
  __shared__ float rn[GS][256];
  __shared__ float rd[GS][256];

  const int b     = blockIdx.x;
  const int tid   = threadIdx.x;
  const int fl    = tid & 255;
  const int slice = __builtin_amdgcn_readfirstlane(tid >> 8);  // wave-uniform SGPR
  const int fi    = blockIdx.y * 256 + fl;

  const float s = qs[b * F + fi];

  int cnts[NSEG];
  float km = -3.4e38f, kn = 3.4e38f;
  int ntot = 0;
  float vstot = 0.f;
#pragma unroll
  for (int g2 = 0; g2 < NSEG; ++g2) {
    cnts[g2] = cnt2[b * NSEG + g2];
    ntot += cnts[g2];
    km = fmaxf(km, kmax2[b * NSEG + g2]);
    kn = fminf(kn, kmin2[b * NSEG + g2]);
    vstot += vsum2[b * NSEG + g2];
  }

  const float L2E = 1.44269504088896f;
  const float se  = s * L2E;
  const float nm2 = -se * ((s >= 0.f) ? km : kn);

  float n0 = 0.f, n1 = 0.f, n2 = 0.f, n3 = 0.f;
  float d0 = 0.f, d1 = 0.f, d2 = 0.f, d3 = 0.f;
  const float* kvbase = kvc + (size_t)b * 2 * F;
#pragma unroll
  for (int seg = 0; seg < NSEG; ++seg) {
    const int cnt   = cnts[seg];
    const int quads = cnt >> 1;                 // float4 groups (2 pairs)
    const int q0 = (slice * quads) / GS;
    const int q1 = ((slice + 1) * quads) / GS;
    const float4* bp = (const float4*)(kvbase + seg * 2 * SEGG);
    int q = q0;
    for (; q + 4 <= q1; q += 4) {               // 16 floats via uniform loads
      float4 p0 = bp[q];
      float4 p1 = bp[q + 1];
      float4 p2 = bp[q + 2];
      float4 p3 = bp[q + 3];
      float e0 = EXP2(fmaf(se, p0.x, nm2));
      float e1 = EXP2(fmaf(se, p0.z, nm2));
      float e2 = EXP2(fmaf(se, p1.x, nm2));
      float e3 = EXP2(fmaf(se, p1.z, nm2));
      float e4 = EXP2(fmaf(se, p2.x, nm2));
      float e5 = EXP2(fmaf(se, p2.z, nm2));
      float e6 = EXP2(fmaf(se, p3.x, nm2));
      float e7 = EXP2(fmaf(se, p3.z, nm2));
      n0 = fmaf(e0, p0.y, n0); d0 += e0;
      n1 = fmaf(e1, p0.w, n1); d1 += e1;
      n2 = fmaf(e2, p1.y, n2); d2 += e2;
      n3 = fmaf(e3, p1.w, n3); d3 += e3;
      n0 = fmaf(e4, p2.y, n0); d0 += e4;
      n1 = fmaf(e5, p2.w, n1); d1 += e5;
      n2 = fmaf(e6, p3.y, n2); d2 += e6;
      n3 = fmaf(e7, p3.w, n3); d3 += e7;
    }
    for (; q < q1; ++q) {
      float4 p0 = bp[q];
      float e0 = EXP2(fmaf(se, p0.x, nm2));
      float e1 = EXP2(fmaf(se, p0.z, nm2));
      n0 = fmaf(e0, p0.y, n0); d0 += e0;
      n1 = fmaf(e1, p0.w, n1); d1 += e1;
    }
    if ((slice == GS - 1) && (cnt & 1)) {       // odd tail pair
      float2 p = *(const float2*)(kvbase + seg * 2 * SEGG + 2 * (cnt - 1));
      float e = EXP2(fmaf(se, p.x, nm2));
      n2 = fmaf(e, p.y, n2); d2 += e;
    }
  }
  rn[slice][fl] = (n0 + n1) + (n2 + n3);
  rd[slice][fl] = (d0 + d1) + (d2 + d3);
  __syncthreads();
  if (slice == 0) {
    float N = (rn[0][fl] + rn[1][fl]) + (rn[2][fl] + rn[3][fl]);
    float D = (rd[0][fl] + rd[1][fl]) + (rd[2][fl] + rd[3][fl]);
    out[b * F + fi] = (ntot > 0) ? (N / D) : (vstot * (1.0f / (float)F));
  }
}

extern "C" void kernel_launch(void* const* d_in, const int* in_sizes, int n_in,
                              void* d_out, int out_size, void* d_ws, size_t ws_size,
                              hipStream_t stream) {
  const float* x  = (const float*)d_in[0];
  const int* mask = (const int*)d_in[1];
  const float* Wq = (const float*)d_in[2];
  const float* Wk = (const float*)d_in[3];
  const float* Wv = (const float*)d_in[4];
  float* out = (float*)d_out;

  float* part  = (float*)d_ws;                 // 6.3 MB
  float* kvc   = part + PART_FLOATS;           // 1 MB
  float* qs    = kvc + KVC_FLOATS;             // 0.5 MB
  float* vsum2 = qs + QS_FLOATS;               // B*NSEG floats
  float* kmx2  = vsum2 + B * NSEG;
  float* kmn2  = kmx2 + B * NSEG;
  int*   cnt2  = (int*)(kmn2 + B * NSEG);

  dim3 gg(F / BN, KSPLIT, 3);
  qkv_gemm_kernel<<<gg, 256, 0, stream>>>(x, Wq, Wk, Wv, part);
  dim3 gp(B, NSEG);
  prep_kernel<<<gp, 256, 0, stream>>>(part, mask, kvc, qs, vsum2, kmx2, kmn2, cnt2);
  dim3 ga(B, F / 256);
  attn_kernel<<<ga, 1024, 0, stream>>>(qs, kvc, vsum2, kmx2, kmn2, cnt2, out);
}

// Round 4
// 121.236 us; speedup vs baseline: 1.5834x; 1.0116x over previous
//
#include <hip/hip_runtime.h>
#include <hip/hip_bf16.h>

#define B 64
#define F 2048
#define BN 32
#define BK 32
#define KSPLIT 4
#define KCHUNK (F / KSPLIT)   // 512
#define NITER (KCHUNK / BK)   // 16
#define LDSW 40               // LDS row stride in shorts (80 B, 16B-aligned rows)
#define GS 4                  // g-slices per attn block

typedef __attribute__((ext_vector_type(8))) short bf16x8;
typedef __attribute__((ext_vector_type(4))) float f32x4;

#define PART_FLOATS (KSPLIT * 3 * B * F)  // 6.3 MB

#if __has_builtin(__builtin_amdgcn_exp2f)
#define EXP2(x) __builtin_amdgcn_exp2f(x)   // raw v_exp_f32, no denorm expansion
#else
#define EXP2(x) exp2f(x)
#endif

// RTZ hi/lo split of two floats, packed via v_perm. 3 ops/float.
__device__ __forceinline__ void split2(float f0, float f1, int& hi, int& lo) {
  union { float f; unsigned u; } a, b;
  a.f = f0; b.f = f1;
  union { unsigned u; float f; } ha, hb;
  ha.u = a.u & 0xFFFF0000u;
  hb.u = b.u & 0xFFFF0000u;
  union { float f; unsigned u; } la, lb;
  la.f = f0 - ha.f;
  lb.f = f1 - hb.f;
  hi = (int)__builtin_amdgcn_perm(b.u, a.u, 0x07060302u);
  lo = (int)__builtin_amdgcn_perm(lb.u, la.u, 0x07060302u);
}

// C[b,f] = sum_k x[b,k]*W[f,k], bf16 hi/lo split (3 MFMAs ~ fp32 accuracy).
// Split-K partials -> part[(kb*3+mat)*B*F]. LDS double-buffered, 1 barrier/iter.
// BN=32 x KSPLIT=4 -> 768 blocks = 3/CU for BW saturation (verified config).
// NO inter-block sync (round-2's fused handoff caused an L2-invalidate storm).
__global__ __launch_bounds__(256) void qkv_gemm_kernel(
    const float* __restrict__ x, const float* __restrict__ Wq,
    const float* __restrict__ Wk, const float* __restrict__ Wv,
    float* __restrict__ part) {
  __shared__ __align__(16) short xs_hi[2][B][LDSW];
  __shared__ __align__(16) short xs_lo[2][B][LDSW];
  __shared__ __align__(16) short ws_hi[2][BN][LDSW];
  __shared__ __align__(16) short ws_lo[2][BN][LDSW];

  const int tid  = threadIdx.x;
  const int f0   = blockIdx.x * BN;
  const int kb   = blockIdx.y;
  const int mat  = blockIdx.z;
  const float* W = (mat == 0) ? Wq : (mat == 1) ? Wk : Wv;

  const int lrow = tid >> 2;           // x staging row 0..63
  const int lc0  = (tid & 3) << 3;     // x staging col (shorts) 0,8,16,24
  const int wrow = tid >> 3;           // W staging row 0..31
  const int wc0  = (tid & 7) << 2;     // W staging col (shorts) 0,4,...,28

  const int wave = tid >> 6;
  const int lane = tid & 63;
  const int l15  = lane & 15;
  const int quad = lane >> 4;

  const float* xg = x + lrow * F + kb * KCHUNK + lc0;
  const float* wg = W + (f0 + wrow) * F + kb * KCHUNK + wc0;

  f32x4 acc[2];
#pragma unroll
  for (int i = 0; i < 2; ++i) acc[i] = (f32x4){0.f, 0.f, 0.f, 0.f};

  float4 px[2][2], pw[2];
  px[0][0] = *(const float4*)(xg);
  px[0][1] = *(const float4*)(xg + 4);
  pw[0]    = *(const float4*)(wg);

#pragma unroll
  for (int it = 0; it < NITER; ++it) {
    const int cur = it & 1, nxt = cur ^ 1;
    if (it + 1 < NITER) {  // prefetch next chunk into alternate regs
      const float* xp = xg + (it + 1) * BK;
      px[nxt][0] = *(const float4*)(xp);
      px[nxt][1] = *(const float4*)(xp + 4);
      pw[nxt]    = *(const float4*)(wg + (it + 1) * BK);
    }
    int4 xh, xl;
    int2 wh, wl;
    split2(px[cur][0].x, px[cur][0].y, xh.x, xl.x);
    split2(px[cur][0].z, px[cur][0].w, xh.y, xl.y);
    split2(px[cur][1].x, px[cur][1].y, xh.z, xl.z);
    split2(px[cur][1].z, px[cur][1].w, xh.w, xl.w);
    split2(pw[cur].x, pw[cur].y, wh.x, wl.x);
    split2(pw[cur].z, pw[cur].w, wh.y, wl.y);
    *(int4*)&xs_hi[cur][lrow][lc0] = xh;
    *(int4*)&xs_lo[cur][lrow][lc0] = xl;
    *(int2*)&ws_hi[cur][wrow][wc0] = wh;
    *(int2*)&ws_lo[cur][wrow][wc0] = wl;
    __syncthreads();  // writes[cur] visible; prior iter's reads drained

    bf16x8 a_hi = *(const bf16x8*)&xs_hi[cur][(wave << 4) + l15][quad << 3];
    bf16x8 a_lo = *(const bf16x8*)&xs_lo[cur][(wave << 4) + l15][quad << 3];
#pragma unroll
    for (int nt = 0; nt < 2; ++nt) {
      bf16x8 b_hi = *(const bf16x8*)&ws_hi[cur][(nt << 4) + l15][quad << 3];
      bf16x8 b_lo = *(const bf16x8*)&ws_lo[cur][(nt << 4) + l15][quad << 3];
      acc[nt] = __builtin_amdgcn_mfma_f32_16x16x32_bf16(a_hi, b_hi, acc[nt], 0, 0, 0);
      acc[nt] = __builtin_amdgcn_mfma_f32_16x16x32_bf16(a_hi, b_lo, acc[nt], 0, 0, 0);
      acc[nt] = __builtin_amdgcn_mfma_f32_16x16x32_bf16(a_lo, b_hi, acc[nt], 0, 0, 0);
    }
  }

  // epilogue: C/D layout col=lane&15, row=quad*4+reg
  float* outp = part + (size_t)(kb * 3 + mat) * B * F;
#pragma unroll
  for (int nt = 0; nt < 2; ++nt) {
    int f = f0 + (nt << 4) + l15;
#pragma unroll
    for (int r = 0; r < 4; ++r) {
      int brow = (wave << 4) + (quad << 2) + r;
      outp[brow * F + f] = acc[nt][r];
    }
  }
}

// attended[b,f], prep fused in. Per (b, yblk of 256 f's):
//  1. each thread sums the KSPLIT k/v partials for 2 g's (coalesced float2),
//  2. ballot-compacts active pairs into a 16 KB LDS stream (block-local order;
//     softmax sums are commutative so order only perturbs fp rounding),
//  3. wave+block reduce kmax/kmin/vsum(all), one barrier,
//  4. verified exp loop (3 VALU + 1 v_exp per element) over the LDS stream
//     via broadcast ds_read_b128 (all lanes same address -> conflict-free).
// q[b,fi] summed from partials inline (qs buffer eliminated).
// Grid (B, 8): the 8 y-blocks of a b are 64 apart in dispatch order -> same
// XCD under %8 round-robin -> each b's 64 KB partial slab is read ~once/XCD.
__global__ __launch_bounds__(1024, 8) void attn_kernel(
    const float* __restrict__ part, const int* __restrict__ mask,
    float* __restrict__ out) {
  __shared__ __align__(16) float kvs[2 * F];   // 16 KB compacted (k,v) stream
  __shared__ float rn[GS][256];
  __shared__ float rd[GS][256];
  __shared__ float swv[16], swm[16], swn[16];
  __shared__ int scnt;

  const int b     = blockIdx.x;
  const int tid   = threadIdx.x;
  const int fl    = tid & 255;
  const int slice = __builtin_amdgcn_readfirstlane(tid >> 8);  // wave-uniform
  const int fi    = blockIdx.y * 256 + fl;
  const int wid   = tid >> 6;
  const int lane  = tid & 63;

  if (tid == 0) scnt = 0;
  __syncthreads();

  // q prologue: sum split-K q partials for this (b, fi)
  float s = 0.f;
#pragma unroll
  for (int p = 0; p < KSPLIT; ++p) s += part[((p * 3 + 0) * B + b) * F + fi];

  // stage+reduce k/v partials for 2 g's, then compact
  const int g0 = tid << 1;
  float2 k2 = {0.f, 0.f}, v2 = {0.f, 0.f};
#pragma unroll
  for (int p = 0; p < KSPLIT; ++p) {
    const float2 kp = *(const float2*)&part[((p * 3 + 1) * B + b) * F + g0];
    const float2 vp = *(const float2*)&part[((p * 3 + 2) * B + b) * F + g0];
    k2.x += kp.x; k2.y += kp.y;
    v2.x += vp.x; v2.y += vp.y;
  }
  float vs = v2.x + v2.y;                       // all v (fallback path)

  const int2 m2 = *(const int2*)&mask[b * F + g0];
  const bool a0 = (m2.x != 0), a1 = (m2.y != 0);
  const unsigned long long bal0 = __ballot(a0);
  const unsigned long long bal1 = __ballot(a1);
  const int tot = __popcll(bal0) + __popcll(bal1);
  int base = 0;
  if (lane == 0) base = atomicAdd(&scnt, tot);
  base = __shfl(base, 0);

  const unsigned long long ltm = (1ull << lane) - 1ull;
  float kmx = -3.4e38f, kmn = 3.4e38f;
  if (a0) {
    int pos = base + __popcll(bal0 & ltm);
    *(float2*)&kvs[2 * pos] = (float2){k2.x, v2.x};
    kmx = fmaxf(kmx, k2.x); kmn = fminf(kmn, k2.x);
  }
  if (a1) {
    int pos = base + __popcll(bal0) + __popcll(bal1 & ltm);
    *(float2*)&kvs[2 * pos] = (float2){k2.y, v2.y};
    kmx = fmaxf(kmx, k2.y); kmn = fminf(kmn, k2.y);
  }

#pragma unroll
  for (int o = 32; o > 0; o >>= 1) {
    vs += __shfl_xor(vs, o);
    kmx = fmaxf(kmx, __shfl_xor(kmx, o));
    kmn = fminf(kmn, __shfl_xor(kmn, o));
  }
  if (lane == 0) { swv[wid] = vs; swm[wid] = kmx; swn[wid] = kmn; }
  __syncthreads();   // compacted stream + reductions visible

  const int ntot = scnt;
  float km = -3.4e38f, kn = 3.4e38f, vstot = 0.f;
#pragma unroll
  for (int w = 0; w < 16; ++w) {
    km = fmaxf(km, swm[w]);
    kn = fminf(kn, swn[w]);
    vstot += swv[w];
  }

  const float L2E = 1.44269504088896f;
  const float se  = s * L2E;
  const float nm2 = -se * ((s >= 0.f) ? km : kn);

  float n0 = 0.f, n1 = 0.f, n2 = 0.f, n3 = 0.f;
  float d0 = 0.f, d1 = 0.f, d2 = 0.f, d3 = 0.f;
  {
    const int quads = ntot >> 1;                // float4 groups (2 pairs)
    const int q0 = (slice * quads) / GS;
    const int q1 = ((slice + 1) * quads) / GS;
    const float4* bp = (const float4*)kvs;
    int q = q0;
    for (; q + 4 <= q1; q += 4) {               // 4x ds_read_b128 broadcast
      float4 p0 = bp[q];
      float4 p1 = bp[q + 1];
      float4 p2 = bp[q + 2];
      float4 p3 = bp[q + 3];
      float e0 = EXP2(fmaf(se, p0.x, nm2));
      float e1 = EXP2(fmaf(se, p0.z, nm2));
      float e2 = EXP2(fmaf(se, p1.x, nm2));
      float e3 = EXP2(fmaf(se, p1.z, nm2));
      float e4 = EXP2(fmaf(se, p2.x, nm2));
      float e5 = EXP2(fmaf(se, p2.z, nm2));
      float e6 = EXP2(fmaf(se, p3.x, nm2));
      float e7 = EXP2(fmaf(se, p3.z, nm2));
      n0 = fmaf(e0, p0.y, n0); d0 += e0;
      n1 = fmaf(e1, p0.w, n1); d1 += e1;
      n2 = fmaf(e2, p1.y, n2); d2 += e2;
      n3 = fmaf(e3, p1.w, n3); d3 += e3;
      n0 = fmaf(e4, p2.y, n0); d0 += e4;
      n1 = fmaf(e5, p2.w, n1); d1 += e5;
      n2 = fmaf(e6, p3.y, n2); d2 += e6;
      n3 = fmaf(e7, p3.w, n3); d3 += e7;
    }
    for (; q < q1; ++q) {
      float4 p0 = bp[q];
      float e0 = EXP2(fmaf(se, p0.x, nm2));
      float e1 = EXP2(fmaf(se, p0.z, nm2));
      n0 = fmaf(e0, p0.y, n0); d0 += e0;
      n1 = fmaf(e1, p0.w, n1); d1 += e1;
    }
    if ((slice == GS - 1) && (ntot & 1)) {      // odd tail pair
      float2 p = *(const float2*)(kvs + 2 * (ntot - 1));
      float e = EXP2(fmaf(se, p.x, nm2));
      n2 = fmaf(e, p.y, n2); d2 += e;
    }
  }
  rn[slice][fl] = (n0 + n1) + (n2 + n3);
  rd[slice][fl] = (d0 + d1) + (d2 + d3);
  __syncthreads();
  if (slice == 0) {
    float N = (rn[0][fl] + rn[1][fl]) + (rn[2][fl] + rn[3][fl]);
    float D = (rd[0][fl] + rd[1][fl]) + (rd[2][fl] + rd[3][fl]);
    out[b * F + fi] = (ntot > 0) ? (N / D) : (vstot * (1.0f / (float)F));
  }
}

extern "C" void kernel_launch(void* const* d_in, const int* in_sizes, int n_in,
                              void* d_out, int out_size, void* d_ws, size_t ws_size,
                              hipStream_t stream) {
  const float* x  = (const float*)d_in[0];
  const int* mask = (const int*)d_in[1];
  const float* Wq = (const float*)d_in[2];
  const float* Wk = (const float*)d_in[3];
  const float* Wv = (const float*)d_in[4];
  float* out = (float*)d_out;

  float* part = (float*)d_ws;                  // 6.3 MB

  dim3 gg(F / BN, KSPLIT, 3);
  qkv_gemm_kernel<<<gg, 256, 0, stream>>>(x, Wq, Wk, Wv, part);
  dim3 ga(B, F / 256);
  attn_kernel<<<ga, 1024, 0, stream>>>(part, mask, out);
}

// Round 5
// 119.717 us; speedup vs baseline: 1.6035x; 1.0127x over previous
//
#include <hip/hip_runtime.h>
#include <hip/hip_bf16.h>

#define B 64
#define F 2048
#define BN 32
#define BK 32
#define KSPLIT 4
#define KCHUNK (F / KSPLIT)   // 512
#define NITER (KCHUNK / BK)   // 16
#define LDSW 40               // LDS row stride in shorts (80 B, 16B-aligned rows)

typedef __attribute__((ext_vector_type(8))) short bf16x8;
typedef __attribute__((ext_vector_type(4))) float f32x4;

#define PART_FLOATS (KSPLIT * 3 * B * F)  // 6.3 MB

#if __has_builtin(__builtin_amdgcn_exp2f)
#define EXP2(x) __builtin_amdgcn_exp2f(x)   // raw v_exp_f32, no denorm expansion
#else
#define EXP2(x) exp2f(x)
#endif

// RTZ hi/lo split of two floats, packed via v_perm. 3 ops/float.
__device__ __forceinline__ void split2(float f0, float f1, int& hi, int& lo) {
  union { float f; unsigned u; } a, b;
  a.f = f0; b.f = f1;
  union { unsigned u; float f; } ha, hb;
  ha.u = a.u & 0xFFFF0000u;
  hb.u = b.u & 0xFFFF0000u;
  union { float f; unsigned u; } la, lb;
  la.f = f0 - ha.f;
  lb.f = f1 - hb.f;
  hi = (int)__builtin_amdgcn_perm(b.u, a.u, 0x07060302u);
  lo = (int)__builtin_amdgcn_perm(lb.u, la.u, 0x07060302u);
}

// C[b,f] = sum_k x[b,k]*W[f,k], bf16 hi/lo split (3 MFMAs ~ fp32 accuracy).
// Split-K partials -> part[(kb*3+mat)*B*F]. LDS double-buffered, 1 barrier/iter.
// BN=32 x KSPLIT=4 -> 768 blocks = 3/CU for BW saturation (verified config).
// NO inter-block sync (round-2's fused handoff caused an L2-invalidate storm).
__global__ __launch_bounds__(256) void qkv_gemm_kernel(
    const float* __restrict__ x, const float* __restrict__ Wq,
    const float* __restrict__ Wk, const float* __restrict__ Wv,
    float* __restrict__ part) {
  __shared__ __align__(16) short xs_hi[2][B][LDSW];
  __shared__ __align__(16) short xs_lo[2][B][LDSW];
  __shared__ __align__(16) short ws_hi[2][BN][LDSW];
  __shared__ __align__(16) short ws_lo[2][BN][LDSW];

  const int tid  = threadIdx.x;
  const int f0   = blockIdx.x * BN;
  const int kb   = blockIdx.y;
  const int mat  = blockIdx.z;
  const float* W = (mat == 0) ? Wq : (mat == 1) ? Wk : Wv;

  const int lrow = tid >> 2;           // x staging row 0..63
  const int lc0  = (tid & 3) << 3;     // x staging col (shorts) 0,8,16,24
  const int wrow = tid >> 3;           // W staging row 0..31
  const int wc0  = (tid & 7) << 2;     // W staging col (shorts) 0,4,...,28

  const int wave = tid >> 6;
  const int lane = tid & 63;
  const int l15  = lane & 15;
  const int quad = lane >> 4;

  const float* xg = x + lrow * F + kb * KCHUNK + lc0;
  const float* wg = W + (f0 + wrow) * F + kb * KCHUNK + wc0;

  f32x4 acc[2];
#pragma unroll
  for (int i = 0; i < 2; ++i) acc[i] = (f32x4){0.f, 0.f, 0.f, 0.f};

  float4 px[2][2], pw[2];
  px[0][0] = *(const float4*)(xg);
  px[0][1] = *(const float4*)(xg + 4);
  pw[0]    = *(const float4*)(wg);

#pragma unroll
  for (int it = 0; it < NITER; ++it) {
    const int cur = it & 1, nxt = cur ^ 1;
    if (it + 1 < NITER) {  // prefetch next chunk into alternate regs
      const float* xp = xg + (it + 1) * BK;
      px[nxt][0] = *(const float4*)(xp);
      px[nxt][1] = *(const float4*)(xp + 4);
      pw[nxt]    = *(const float4*)(wg + (it + 1) * BK);
    }
    int4 xh, xl;
    int2 wh, wl;
    split2(px[cur][0].x, px[cur][0].y, xh.x, xl.x);
    split2(px[cur][0].z, px[cur][0].w, xh.y, xl.y);
    split2(px[cur][1].x, px[cur][1].y, xh.z, xl.z);
    split2(px[cur][1].z, px[cur][1].w, xh.w, xl.w);
    split2(pw[cur].x, pw[cur].y, wh.x, wl.x);
    split2(pw[cur].z, pw[cur].w, wh.y, wl.y);
    *(int4*)&xs_hi[cur][lrow][lc0] = xh;
    *(int4*)&xs_lo[cur][lrow][lc0] = xl;
    *(int2*)&ws_hi[cur][wrow][wc0] = wh;
    *(int2*)&ws_lo[cur][wrow][wc0] = wl;
    __syncthreads();  // writes[cur] visible; prior iter's reads drained

    bf16x8 a_hi = *(const bf16x8*)&xs_hi[cur][(wave << 4) + l15][quad << 3];
    bf16x8 a_lo = *(const bf16x8*)&xs_lo[cur][(wave << 4) + l15][quad << 3];
#pragma unroll
    for (int nt = 0; nt < 2; ++nt) {
      bf16x8 b_hi = *(const bf16x8*)&ws_hi[cur][(nt << 4) + l15][quad << 3];
      bf16x8 b_lo = *(const bf16x8*)&ws_lo[cur][(nt << 4) + l15][quad << 3];
      acc[nt] = __builtin_amdgcn_mfma_f32_16x16x32_bf16(a_hi, b_hi, acc[nt], 0, 0, 0);
      acc[nt] = __builtin_amdgcn_mfma_f32_16x16x32_bf16(a_hi, b_lo, acc[nt], 0, 0, 0);
      acc[nt] = __builtin_amdgcn_mfma_f32_16x16x32_bf16(a_lo, b_hi, acc[nt], 0, 0, 0);
    }
  }

  // epilogue: C/D layout col=lane&15, row=quad*4+reg
  float* outp = part + (size_t)(kb * 3 + mat) * B * F;
#pragma unroll
  for (int nt = 0; nt < 2; ++nt) {
    int f = f0 + (nt << 4) + l15;
#pragma unroll
    for (int r = 0; r < 4; ++r) {
      int brow = (wave << 4) + (quad << 2) + r;
      outp[brow * F + f] = acc[nt][r];
    }
  }
}

// attended[b,f], prep fused. Per (b, yblk of 256 f's):
//  1. each thread sums the KSPLIT k/v partials for 2 g's, ballot-compacts
//     active pairs into a 16 KB LDS stream, wave+block reduce kmax/kmin/vsum.
//  2. exp phase, LDS-issue-minimized: 16 waves each own a DISTINCT 1/16 slice
//     of the stream (no slice duplication); each lane serves 4 fi (r*64+lane)
//     against each broadcast quad -> 32 ds_read_b128 per wave (was 128 with
//     4x duplication), VALU:LDS = 24:1 so the per-CU LDS pipe is off the
//     critical path. Partial (n,d) in rn/rd[16][256]; 256-thread final fold.
__global__ __launch_bounds__(1024, 8) void attn_kernel(
    const float* __restrict__ part, const int* __restrict__ mask,
    float* __restrict__ out) {
  __shared__ __align__(16) float kvs[2 * F];   // 16 KB compacted (k,v) stream
  __shared__ float rn[16][256];                // 16 KB slice partials
  __shared__ float rd[16][256];                // 16 KB
  __shared__ float swv[16], swm[16], swn[16];
  __shared__ int scnt;

  const int b    = blockIdx.x;
  const int tid  = threadIdx.x;
  const int wid  = __builtin_amdgcn_readfirstlane(tid >> 6);  // wave-uniform
  const int lane = tid & 63;

  if (tid == 0) scnt = 0;
  __syncthreads();

  // q prologue: each lane owns 4 fi (r*64+lane); issue early, consumed post-barrier
  float qsum[4];
#pragma unroll
  for (int r = 0; r < 4; ++r) {
    const int fi = blockIdx.y * 256 + (r << 6) + lane;
    float s = 0.f;
#pragma unroll
    for (int p = 0; p < KSPLIT; ++p) s += part[((p * 3 + 0) * B + b) * F + fi];
    qsum[r] = s;
  }

  // stage+reduce k/v partials for 2 g's, then compact
  const int g0 = tid << 1;
  float2 k2 = {0.f, 0.f}, v2 = {0.f, 0.f};
#pragma unroll
  for (int p = 0; p < KSPLIT; ++p) {
    const float2 kp = *(const float2*)&part[((p * 3 + 1) * B + b) * F + g0];
    const float2 vp = *(const float2*)&part[((p * 3 + 2) * B + b) * F + g0];
    k2.x += kp.x; k2.y += kp.y;
    v2.x += vp.x; v2.y += vp.y;
  }
  float vs = v2.x + v2.y;                       // all v (fallback path)

  const int2 m2 = *(const int2*)&mask[b * F + g0];
  const bool a0 = (m2.x != 0), a1 = (m2.y != 0);
  const unsigned long long bal0 = __ballot(a0);
  const unsigned long long bal1 = __ballot(a1);
  const int tot = __popcll(bal0) + __popcll(bal1);
  int base = 0;
  if (lane == 0) base = atomicAdd(&scnt, tot);
  base = __shfl(base, 0);

  const unsigned long long ltm = (1ull << lane) - 1ull;
  float kmx = -3.4e38f, kmn = 3.4e38f;
  if (a0) {
    int pos = base + __popcll(bal0 & ltm);
    *(float2*)&kvs[2 * pos] = (float2){k2.x, v2.x};
    kmx = fmaxf(kmx, k2.x); kmn = fminf(kmn, k2.x);
  }
  if (a1) {
    int pos = base + __popcll(bal0) + __popcll(bal1 & ltm);
    *(float2*)&kvs[2 * pos] = (float2){k2.y, v2.y};
    kmx = fmaxf(kmx, k2.y); kmn = fminf(kmn, k2.y);
  }

#pragma unroll
  for (int o = 32; o > 0; o >>= 1) {
    vs += __shfl_xor(vs, o);
    kmx = fmaxf(kmx, __shfl_xor(kmx, o));
    kmn = fminf(kmn, __shfl_xor(kmn, o));
  }
  if (lane == 0) { swv[wid] = vs; swm[wid] = kmx; swn[wid] = kmn; }
  __syncthreads();   // compacted stream + reductions visible

  const int ntot = scnt;
  float km = -3.4e38f, kn = 3.4e38f, vstot = 0.f;
#pragma unroll
  for (int w = 0; w < 16; ++w) {
    km = fmaxf(km, swm[w]);
    kn = fminf(kn, swn[w]);
    vstot += swv[w];
  }

  const float L2E = 1.44269504088896f;
  float se[4], nm[4];
#pragma unroll
  for (int r = 0; r < 4; ++r) {
    se[r] = qsum[r] * L2E;
    nm[r] = -se[r] * ((qsum[r] >= 0.f) ? km : kn);
  }

  float n[4] = {0.f, 0.f, 0.f, 0.f};
  float d[4] = {0.f, 0.f, 0.f, 0.f};
  {
    const int quads = ntot >> 1;               // float4 groups (2 pairs)
    const int q0 = (wid * quads) >> 4;         // this wave's distinct slice
    const int q1 = ((wid + 1) * quads) >> 4;
    const float4* bp = (const float4*)kvs;
#pragma unroll 2
    for (int q = q0; q < q1; ++q) {            // broadcast ds_read_b128
      const float4 p = bp[q];
#pragma unroll
      for (int r = 0; r < 4; ++r) {
        float e0 = EXP2(fmaf(se[r], p.x, nm[r]));
        float e1 = EXP2(fmaf(se[r], p.z, nm[r]));
        n[r] = fmaf(e0, p.y, n[r]); d[r] += e0;
        n[r] = fmaf(e1, p.w, n[r]); d[r] += e1;
      }
    }
    if ((wid == 15) && (ntot & 1)) {           // odd tail pair
      const float2 p = *(const float2*)(kvs + 2 * (ntot - 1));
#pragma unroll
      for (int r = 0; r < 4; ++r) {
        float e = EXP2(fmaf(se[r], p.x, nm[r]));
        n[r] = fmaf(e, p.y, n[r]); d[r] += e;
      }
    }
  }
#pragma unroll
  for (int r = 0; r < 4; ++r) {
    rn[wid][(r << 6) + lane] = n[r];
    rd[wid][(r << 6) + lane] = d[r];
  }
  __syncthreads();
  if (tid < 256) {                             // fold 16 slices per fi
    float N = 0.f, D = 0.f;
#pragma unroll
    for (int s = 0; s < 16; ++s) { N += rn[s][tid]; D += rd[s][tid]; }
    out[b * F + blockIdx.y * 256 + tid] =
        (ntot > 0) ? (N / D) : (vstot * (1.0f / (float)F));
  }
}

extern "C" void kernel_launch(void* const* d_in, const int* in_sizes, int n_in,
                              void* d_out, int out_size, void* d_ws, size_t ws_size,
                              hipStream_t stream) {
  const float* x  = (const float*)d_in[0];
  const int* mask = (const int*)d_in[1];
  const float* Wq = (const float*)d_in[2];
  const float* Wk = (const float*)d_in[3];
  const float* Wv = (const float*)d_in[4];
  float* out = (float*)d_out;

  float* part = (float*)d_ws;                  // 6.3 MB

  dim3 gg(F / BN, KSPLIT, 3);
  qkv_gemm_kernel<<<gg, 256, 0, stream>>>(x, Wq, Wk, Wv, part);
  dim3 ga(B, F / 256);
  attn_kernel<<<ga, 1024, 0, stream>>>(part, mask, out);
}